// Round 3
// baseline (200.525 us; speedup 1.0000x reference)
//
#include <hip/hip_runtime.h>

// Multi-step LIF forward (T=4, tau=2, hard reset to 0, v_th=1).
// Forward value of the STE spike is just heaviside(v_charged - 1).
// Each thread owns TWO independent 16B columns per grid-stride iteration
// (8 in-flight loads, 2 independent v-chains) to deepen MLP.
// Pure streaming: 512 MiB in + 512 MiB out, memory-bound.

#define T_STEPS 4

// Native clang vector (not HIP_vector_type) so nontemporal builtins accept it.
typedef float f4 __attribute__((ext_vector_type(4)));

__global__ __launch_bounds__(256) void lif_fwd_kernel(
    const f4* __restrict__ x, f4* __restrict__ out, int bn4) {
    const int stride = gridDim.x * blockDim.x;
    for (int i = blockIdx.x * blockDim.x + threadIdx.x; i < bn4; i += 2 * stride) {
        const int i2 = i + stride;
        const bool has2 = (i2 < bn4);
        f4 v0 = {0.0f, 0.0f, 0.0f, 0.0f};
        f4 v1 = {0.0f, 0.0f, 0.0f, 0.0f};
#pragma unroll
        for (int t = 0; t < T_STEPS; ++t) {
            const size_t base = (size_t)t * (size_t)bn4;
            f4 xa = __builtin_nontemporal_load(&x[base + (size_t)i]);
            f4 xb = has2 ? __builtin_nontemporal_load(&x[base + (size_t)i2])
                         : (f4){0.0f, 0.0f, 0.0f, 0.0f};
            f4 sa, sb;
#pragma unroll
            for (int j = 0; j < 4; ++j) {
                // v_charged = v + (x - v) * 0.5   (matches ref v + (x - v)/tau)
                float vc0 = v0[j] + (xa[j] - v0[j]) * 0.5f;
                bool f0 = (vc0 >= 1.0f);
                sa[j] = f0 ? 1.0f : 0.0f;
                v0[j] = f0 ? 0.0f : vc0;

                float vc1 = v1[j] + (xb[j] - v1[j]) * 0.5f;
                bool f1 = (vc1 >= 1.0f);
                sb[j] = f1 ? 1.0f : 0.0f;
                v1[j] = f1 ? 0.0f : vc1;
            }
            __builtin_nontemporal_store(sa, &out[base + (size_t)i]);
            if (has2) __builtin_nontemporal_store(sb, &out[base + (size_t)i2]);
        }
    }
}

extern "C" void kernel_launch(void* const* d_in, const int* in_sizes, int n_in,
                              void* d_out, int out_size, void* d_ws, size_t ws_size,
                              hipStream_t stream) {
    const float* x = (const float*)d_in[0];
    float* out = (float*)d_out;

    const long long total = (long long)in_sizes[0];   // T*B*N = 134,217,728
    const long long bn = total / T_STEPS;             // B*N = 33,554,432
    const int bn4 = (int)(bn / 4);                    // 16B columns = 8,388,608

    const int block = 256;
    long long want = (bn4 + block - 1) / block;
    int grid = (int)(want < 2048 ? want : 2048);      // grid-stride the rest

    lif_fwd_kernel<<<grid, block, 0, stream>>>(
        (const f4*)x, (f4*)out, bn4);
}